// Round 1
// baseline (226.623 us; speedup 1.0000x reference)
//
#include <hip/hip_runtime.h>
#include <math.h>

// Problem constants: B=8192, N=49, D=3, D3=42, E=128, K=3
#define N_     49
#define D3_    42
#define E_     128
#define WPB    4      // waves per block

// out[b,n,e] = cd[b,n]*U[e] + den[b,n]*V[e] + C[e]   (rank-2 collapse)
//
// v2 structure (latency-attack):
//  - each lane loads ITS OWN point directly from global (12B/lane; points
//    are only 4.8 MB total, partial coalescing is irrelevant) and stages it
//    as one padded float4 -> ONE ds_write_b128 per batch
//  - kNN inner loop reads one uniform ds_read_b128 broadcast per neighbor
//    (was 3 dependent ds_read_b32) -> ~3x fewer LDS ops, shorter chains
//  - ROUNDS=1, 2048 blocks -> up to 8 blocks/CU resident (VGPR pressure is
//    much lower without the prefetch state); TLP across blocks replaces the
//    old round-1/round-0 overlap
//  - threads 0..127 still compute U/V/C -> LDS per block (W_out is 64 KB,
//    L2-resident; redundant compute is ~4 us aggregate)

__global__ __launch_bounds__(256) void fused_all(
        const float* __restrict__ points,
        const float* __restrict__ W_dist,
        const float* __restrict__ b_dist,
        const float* __restrict__ emb,
        const float* __restrict__ W_den,
        const float* __restrict__ b_den,
        const float* __restrict__ W_out,
        const float* __restrict__ b_out,
        float4* __restrict__ out4,
        int B) {
    __shared__ float4 pts4[WPB][N_];             // padded points, b128 reads
    __shared__ __align__(16) float sUVC[3 * E_];

    const int tid  = threadIdx.x;
    const int lane = tid & 63;
    const int w    = tid >> 6;
    const int wid  = blockIdx.x * WPB + w;       // one batch per wave
    const bool v0  = (wid < B);

    // ---- own-point direct load: issue first so it's in flight ----
    const int n = (lane < N_) ? lane : N_ - 1;
    float px = 0.f, py = 0.f, pz = 0.f;
    if (v0) {
        const float* pb = points + (long long)wid * (N_ * 3) + 3 * n;
        px = pb[0]; py = pb[1]; pz = pb[2];
    }

    // ---- rank-2 collapse: threads 0..127 compute U/V/C into LDS ----
    if (tid < E_) {
        const float* embN = emb + N_ * D3_;  // emb[49] (n_valid == N == 49)
        float u = 0.f, vv = 0.f, c = b_out[tid];
        for (int j = 0; j < D3_; ++j) {
            float w0 = W_out[j * E_ + tid];
            float w1 = W_out[(D3_ + j) * E_ + tid];
            float w2 = W_out[(2 * D3_ + j) * E_ + tid];
            u  = fmaf(W_dist[j], w0, u);
            vv = fmaf(W_den[j],  w2, vv);
            c  = fmaf(b_dist[j], w0, c);
            c  = fmaf(embN[j],   w1, c);
            c  = fmaf(b_den[j],  w2, c);
        }
        sUVC[tid]          = u;
        sUVC[E_ + tid]     = vv;
        sUVC[2 * E_ + tid] = c;
    }

    // ---- stage this wave's batch: one b128 write per lane<49 ----
    if (v0 && lane < N_) {
        pts4[w][lane] = make_float4(px, py, pz, 0.f);
    }

    // ---- kNN + centroid (same-wave LDS RAW -> lgkmcnt only) ----
    float cd = 0.f, dn = 0.f;
    if (v0) {
        float sx = 0.f, sy = 0.f, sz = 0.f;
        float t0 = INFINITY, t1 = INFINITY, t2 = INFINITY;
        for (int m = 0; m < N_; ++m) {
            float4 qq = pts4[w][m];              // uniform broadcast b128
            sx += qq.x; sy += qq.y; sz += qq.z;
            float dx = px - qq.x, dy = py - qq.y, dz = pz - qq.z;
            float d2 = fmaf(dx, dx, fmaf(dy, dy, dz * dz));
            if (m != n) {
                if (d2 < t0)      { t2 = t1; t1 = t0; t0 = d2; }
                else if (d2 < t1) { t2 = t1; t1 = d2; }
                else if (d2 < t2) { t2 = d2; }
            }
        }
        const float inv = 1.0f / (float)N_;
        float cx = sx * inv, cy = sy * inv, cz = sz * inv;
        float ex = px - cx, ey = py - cy, ez = pz - cz;
        cd = sqrtf(fmaf(ex, ex, fmaf(ey, ey, ez * ez)));
        dn = (sqrtf(t0) + sqrtf(t1) + sqrtf(t2)) * (1.0f / 3.0f);
    }

    // ---- one barrier: U/V/C visibility ----
    __syncthreads();
    const int q = lane & 31;
    const float4 u4 = *(const float4*)&sUVC[4 * q];          // 2-way alias:
    const float4 v4 = *(const float4*)&sUVC[E_ + 4 * q];     // broadcast, free
    const float4 c4 = *(const float4*)&sUVC[2 * E_ + 4 * q];

    // ---- stores: 25 wave-wide float4 iterations (1 KiB contiguous each) ----
    if (v0) {
        float4* ob = out4 + (long long)wid * (N_ * 32);
#pragma unroll
        for (int j = 0; j < 25; ++j) {
            int row = 2 * j + (lane >> 5);
            float a = __shfl(cd, row);
            float d = __shfl(dn, row);
            if (row < N_) {
                float4 r;
                r.x = fmaf(a, u4.x, fmaf(d, v4.x, c4.x));
                r.y = fmaf(a, u4.y, fmaf(d, v4.y, c4.y));
                r.z = fmaf(a, u4.z, fmaf(d, v4.z, c4.z));
                r.w = fmaf(a, u4.w, fmaf(d, v4.w, c4.w));
                ob[row * 32 + q] = r;
            }
        }
    }
}

extern "C" void kernel_launch(void* const* d_in, const int* in_sizes, int n_in,
                              void* d_out, int out_size, void* d_ws, size_t ws_size,
                              hipStream_t stream) {
    const float* points = (const float*)d_in[0];
    const float* W_dist = (const float*)d_in[1];
    const float* b_dist = (const float*)d_in[2];
    const float* emb    = (const float*)d_in[3];
    const float* W_den  = (const float*)d_in[4];
    const float* b_den  = (const float*)d_in[5];
    const float* W_out  = (const float*)d_in[6];
    const float* b_out  = (const float*)d_in[7];

    const int B = in_sizes[0] / (N_ * 3);
    const int nblocks = (B + WPB - 1) / WPB;  // 2048 for B=8192

    fused_all<<<nblocks, 64 * WPB, 0, stream>>>(
        points, W_dist, b_dist, emb, W_den, b_den, W_out, b_out,
        (float4*)d_out, B);
}